// Round 1
// baseline (242.241 us; speedup 1.0000x reference)
//
#include <hip/hip_runtime.h>

// ---------------------------------------------------------------------------
// loss = 0.5*(ce(hard) + relu(ce(mean)-R)),  logits = (inputs @ features^T)/TEMP
// B=256 rows, D=256, features rows = 131072 (first 65536 = "mean" half).
// Memory-bound: features (134 MB fp32) must stream from HBM exactly once.
// Matmul on f16 MFMA (16x16x32), exp-accumulate with fixed offset 20
// (logit <= 20 since all rows are unit-norm), partials composed additively.
// ---------------------------------------------------------------------------

typedef _Float16 half8 __attribute__((ext_vector_type(8)));
typedef _Float16 half4v __attribute__((ext_vector_type(4)));
typedef float float4v __attribute__((ext_vector_type(4)));

#define BROWS 256       // batch rows (M)
#define DDIM 256        // reduction (K)
#define NCOLS 131072    // total feature rows (2N)
#define NHALF 65536
#define CPB 512         // columns per block
#define TN 64           // columns per tile
#define NTILES (CPB / TN)          // 8
#define NBLOCKS (NCOLS / CPB)      // 256
#define THREADS 512
#define ROWB 512                   // bytes per LDS tile row (256 halves)
#define LDS_TILE (TN * ROWB)       // 32768 B

// XOR-swizzled LDS address: 16B chunks within a column's 512B row are
// permuted by (col & 7) so the 16-lane b128 frag read is conflict-free.
__device__ __forceinline__ int lds_addr(int col, int chunk) {
    return col * ROWB + ((chunk ^ (col & 7)) << 4);
}

__global__ __launch_bounds__(THREADS)
void gemm_lse_kernel(const float* __restrict__ A,   // [256][256]
                     const float* __restrict__ F,   // [131072][256]
                     float* __restrict__ partial)   // [NBLOCKS][256]
{
    __shared__ __align__(16) char lds[2 * LDS_TILE];

    const int tid  = threadIdx.x;
    const int lane = tid & 63;
    const int w    = tid >> 6;       // wave 0..7  -> row band w*32
    const int m    = lane & 15;      // MFMA row/col within 16
    const int kq   = lane >> 4;      // k-quad 0..3
    const int colBase = blockIdx.x * CPB;
    const int rBase   = w * 32;

    // ---- prefetch tile 0 of F (global -> regs) ----
    const int sc  = tid >> 3;        // staging col 0..63
    const int sub = tid & 7;         // 8 threads per column
    float4v pf[8];
    {
        const float* src = F + (size_t)(colBase)*DDIM + sc * DDIM + sub * 4;
#pragma unroll
        for (int i = 0; i < 8; i++) pf[i] = *(const float4v*)(src + i * 32);
    }

    // ---- A fragments: 32-row band, all K, f16, in registers (64 VGPRs) ----
    // A-operand layout (16x16x32): A[m = lane&15][k = kq*8 + j]
    half8 Af[2][8];
#pragma unroll
    for (int mf = 0; mf < 2; mf++) {
        const int r = rBase + mf * 16 + m;
        const float* ap = A + r * DDIM + kq * 8;
#pragma unroll
        for (int kb = 0; kb < 8; kb++) {
            const float4v x0 = *(const float4v*)(ap + kb * 32);
            const float4v x1 = *(const float4v*)(ap + kb * 32 + 4);
            half8 h;
            h[0] = (_Float16)x0[0]; h[1] = (_Float16)x0[1];
            h[2] = (_Float16)x0[2]; h[3] = (_Float16)x0[3];
            h[4] = (_Float16)x1[0]; h[5] = (_Float16)x1[1];
            h[6] = (_Float16)x1[2]; h[7] = (_Float16)x1[3];
            Af[mf][kb] = h;
        }
    }

    // ---- stage tile 0 into LDS buffer 0 ----
    {
        char* buf = lds;
        const int abase = sc * ROWB + ((sub & 1) << 3);
#pragma unroll
        for (int i = 0; i < 8; i++) {
            const int chunk = (sub >> 1) + i * 4;
            half4v h;
            h[0] = (_Float16)pf[i][0]; h[1] = (_Float16)pf[i][1];
            h[2] = (_Float16)pf[i][2]; h[3] = (_Float16)pf[i][3];
            *(half4v*)(buf + (sc * ROWB + (((chunk ^ (sc & 7)) << 4) | ((sub & 1) << 3)))) = h;
            (void)abase;
        }
    }
    __syncthreads();

    float rowsum[2][4];
#pragma unroll
    for (int mf = 0; mf < 2; mf++)
#pragma unroll
        for (int r = 0; r < 4; r++) rowsum[mf][r] = 0.f;

#pragma unroll 2
    for (int t = 0; t < NTILES; t++) {
        // prefetch next tile (global -> regs); consumed after compute
        if (t + 1 < NTILES) {
            const float* src = F + (size_t)(colBase + (t + 1) * TN) * DDIM + sc * DDIM + sub * 4;
#pragma unroll
            for (int i = 0; i < 8; i++) pf[i] = *(const float4v*)(src + i * 32);
        }

        const char* buf = lds + (t & 1) * LDS_TILE;

        float4v acc[2][4];
#pragma unroll
        for (int mf = 0; mf < 2; mf++)
#pragma unroll
            for (int nf = 0; nf < 4; nf++) acc[mf][nf] = float4v{0.f, 0.f, 0.f, 0.f};

        // K loop: 8 k-blocks of 32
#pragma unroll
        for (int kb = 0; kb < 8; kb++) {
            half8 Bf[4];
#pragma unroll
            for (int nf = 0; nf < 4; nf++) {
                const int c = nf * 16 + m;                       // column in tile
                const int chunk = (kb * 4 + kq) ^ (m & 7);      // (c&7)==(m&7)
                Bf[nf] = *(const half8*)(buf + c * ROWB + (chunk << 4));
            }
#pragma unroll
            for (int mf = 0; mf < 2; mf++)
#pragma unroll
                for (int nf = 0; nf < 4; nf++)
                    acc[mf][nf] = __builtin_amdgcn_mfma_f32_16x16x32_f16(
                        Af[mf][kb], Bf[nf], acc[mf][nf], 0, 0, 0);
        }

        // epilogue: exp(logit - 20) folded into per-row sums
        // C/D layout: col = lane&15, row = kq*4 + reg
#pragma unroll
        for (int mf = 0; mf < 2; mf++)
#pragma unroll
            for (int nf = 0; nf < 4; nf++)
#pragma unroll
                for (int r = 0; r < 4; r++)
                    rowsum[mf][r] += __expf(fmaf(acc[mf][nf][r], 20.f, -20.f));

        // write prefetched tile into the other buffer
        if (t + 1 < NTILES) {
            char* wb = lds + ((t + 1) & 1) * LDS_TILE;
#pragma unroll
            for (int i = 0; i < 8; i++) {
                const int chunk = (sub >> 1) + i * 4;
                half4v h;
                h[0] = (_Float16)pf[i][0]; h[1] = (_Float16)pf[i][1];
                h[2] = (_Float16)pf[i][2]; h[3] = (_Float16)pf[i][3];
                *(half4v*)(wb + (sc * ROWB + (((chunk ^ (sc & 7)) << 4) | ((sub & 1) << 3)))) = h;
            }
        }
        __syncthreads();
    }

    // reduce rowsum across the 16 lanes sharing each row (lane&15 varies)
#pragma unroll
    for (int mf = 0; mf < 2; mf++)
#pragma unroll
        for (int r = 0; r < 4; r++) {
            float s = rowsum[mf][r];
            s += __shfl_xor(s, 1);
            s += __shfl_xor(s, 2);
            s += __shfl_xor(s, 4);
            s += __shfl_xor(s, 8);
            if (m == 0) {
                const int row = rBase + mf * 16 + kq * 4 + r;
                partial[blockIdx.x * BROWS + row] = s;
            }
        }
}

__global__ __launch_bounds__(256)
void finalize_kernel(const float* __restrict__ partial,  // [NBLOCKS][256]
                     const float* __restrict__ A,
                     const float* __restrict__ F,
                     const int* __restrict__ targets,
                     float* __restrict__ out)
{
    const int b = threadIdx.x;  // 256 threads, one per row

    // sum softmax denominators (exp offset = 20) over column-blocks
    float sm0 = 0.f, sm1 = 0.f, sh0 = 0.f, sh1 = 0.f;
#pragma unroll 4
    for (int i = 0; i < 128; i += 2) {
        sm0 += partial[i * BROWS + b];
        sm1 += partial[(i + 1) * BROWS + b];
    }
#pragma unroll 4
    for (int i = 128; i < 256; i += 2) {
        sh0 += partial[i * BROWS + b];
        sh1 += partial[(i + 1) * BROWS + b];
    }
    const float sm = sm0 + sm1, sh = sh0 + sh1;

    // target logits in fp32
    const int t = targets[b];
    const float4v* a4 = (const float4v*)(A + b * DDIM);
    const float4v* fm = (const float4v*)(F + (size_t)t * DDIM);
    const float4v* fh = (const float4v*)(F + (size_t)(t + NHALF) * DDIM);
    float dm = 0.f, dh = 0.f;
#pragma unroll 8
    for (int i = 0; i < 64; i++) {
        const float4v a = a4[i], x = fm[i], y = fh[i];
        dm += a[0] * x[0] + a[1] * x[1] + a[2] * x[2] + a[3] * x[3];
        dh += a[0] * y[0] + a[1] * y[1] + a[2] * y[2] + a[3] * y[3];
    }

    // per-row CE terms: LSE - target_logit ; LSE = 20 + ln(sum)
    float cem = 20.f + __logf(sm) - dm * 20.f;
    float ceh = 20.f + __logf(sh) - dh * 20.f;

#pragma unroll
    for (int msk = 1; msk < 64; msk <<= 1) {
        cem += __shfl_xor(cem, msk);
        ceh += __shfl_xor(ceh, msk);
    }
    __shared__ float sb[8];
    const int wv = threadIdx.x >> 6;
    if ((threadIdx.x & 63) == 0) { sb[wv] = cem; sb[4 + wv] = ceh; }
    __syncthreads();
    if (threadIdx.x == 0) {
        const float cm = (sb[0] + sb[1] + sb[2] + sb[3]) * (1.f / 256.f);
        const float ch = (sb[4] + sb[5] + sb[6] + sb[7]) * (1.f / 256.f);
        const float rl = cm - 0.2f;
        out[0] = 0.5f * (ch + (rl > 0.f ? rl : 0.f));
    }
}

extern "C" void kernel_launch(void* const* d_in, const int* in_sizes, int n_in,
                              void* d_out, int out_size, void* d_ws, size_t ws_size,
                              hipStream_t stream) {
    const float* inputs   = (const float*)d_in[0];   // [256,256] f32
    const int*   targets  = (const int*)d_in[1];     // [256] int
    const float* features = (const float*)d_in[2];   // [131072,256] f32
    float* out = (float*)d_out;
    float* partial = (float*)d_ws;                   // NBLOCKS*256 floats = 256 KB

    gemm_lse_kernel<<<NBLOCKS, THREADS, 0, stream>>>(inputs, features, partial);
    finalize_kernel<<<1, 256, 0, stream>>>(partial, inputs, features, targets, out);
}

// Round 2
// 239.964 us; speedup vs baseline: 1.0095x; 1.0095x over previous
//
#include <hip/hip_runtime.h>

// ---------------------------------------------------------------------------
// loss = 0.5*(ce(hard) + relu(ce(mean)-R)),  logits = (inputs @ features^T)/TEMP
// B=256 rows, D=256, features rows = 131072 (first 65536 = "mean" half).
// Memory-bound: features (134 MB fp32) streams from HBM exactly once.
// f16 MFMA (16x16x32); exp-accumulate with fixed offset 20 (logits <= 20
// since rows are unit-norm); per-block partial denominators compose by +.
// R2: prefetch distance 2 (ping-pong register sets) so the global queue
// never drains across the per-tile barrier; partial transposed to
// [row][block] for coalesced finalize reads.
// ---------------------------------------------------------------------------

typedef _Float16 half8 __attribute__((ext_vector_type(8)));
typedef _Float16 half4v __attribute__((ext_vector_type(4)));
typedef float float4v __attribute__((ext_vector_type(4)));

#define BROWS 256       // batch rows (M)
#define DDIM 256        // reduction (K)
#define NCOLS 131072    // total feature rows (2N)
#define NHALF 65536
#define CPB 512         // columns per block
#define TN 64           // columns per tile
#define NTILES (CPB / TN)          // 8
#define NBLOCKS (NCOLS / CPB)      // 256
#define THREADS 512
#define ROWB 512                   // bytes per LDS tile row (256 halves)
#define LDS_TILE (TN * ROWB)       // 32768 B

__global__ __launch_bounds__(THREADS)
void gemm_lse_kernel(const float* __restrict__ A,   // [256][256]
                     const float* __restrict__ F,   // [131072][256]
                     float* __restrict__ partial)   // [256][NBLOCKS] (transposed)
{
    __shared__ __align__(16) char lds[2 * LDS_TILE];

    const int tid  = threadIdx.x;
    const int lane = tid & 63;
    const int w    = tid >> 6;       // wave 0..7  -> row band w*32
    const int m    = lane & 15;      // MFMA row/col within 16
    const int kq   = lane >> 4;      // k-quad 0..3
    const int colBase = blockIdx.x * CPB;
    const int rBase   = w * 32;

    const int sc  = tid >> 3;        // staging col 0..63
    const int sub = tid & 7;         // 8 threads per column
    const float* srcBase = F + (size_t)(colBase + sc) * DDIM + sub * 4;

    // ---- issue loads for tiles 0 and 1 immediately (distance-2 queue) ----
    float4v pf[2][8];
#pragma unroll
    for (int i = 0; i < 8; i++) pf[0][i] = *(const float4v*)(srcBase + i * 32);
#pragma unroll
    for (int i = 0; i < 8; i++) pf[1][i] = *(const float4v*)(srcBase + TN * DDIM + i * 32);

    // ---- A fragments: 32-row band, all K, f16, in registers (64 VGPRs) ----
    // A-operand layout (16x16x32): A[m = lane&15][k = kq*8 + j]
    half8 Af[2][8];
#pragma unroll
    for (int mf = 0; mf < 2; mf++) {
        const int r = rBase + mf * 16 + m;
        const float* ap = A + r * DDIM + kq * 8;
#pragma unroll
        for (int kb = 0; kb < 8; kb++) {
            const float4v x0 = *(const float4v*)(ap + kb * 32);
            const float4v x1 = *(const float4v*)(ap + kb * 32 + 4);
            half8 h;
            h[0] = (_Float16)x0[0]; h[1] = (_Float16)x0[1];
            h[2] = (_Float16)x0[2]; h[3] = (_Float16)x0[3];
            h[4] = (_Float16)x1[0]; h[5] = (_Float16)x1[1];
            h[6] = (_Float16)x1[2]; h[7] = (_Float16)x1[3];
            Af[mf][kb] = h;
        }
    }

    // ---- stage tile 0 into LDS buffer 0 (waits only pf[0]; pf[1] in flight)
    {
#pragma unroll
        for (int i = 0; i < 8; i++) {
            const int chunk = (sub >> 1) + i * 4;
            half4v h;
            h[0] = (_Float16)pf[0][i][0]; h[1] = (_Float16)pf[0][i][1];
            h[2] = (_Float16)pf[0][i][2]; h[3] = (_Float16)pf[0][i][3];
            *(half4v*)(lds + (sc * ROWB + (((chunk ^ (sc & 7)) << 4) | ((sub & 1) << 3)))) = h;
        }
    }
    __syncthreads();

    float rowsum[2][4];
#pragma unroll
    for (int mf = 0; mf < 2; mf++)
#pragma unroll
        for (int r = 0; r < 4; r++) rowsum[mf][r] = 0.f;

#pragma unroll 2
    for (int t = 0; t < NTILES; t++) {
        // issue loads for tile t+2 into the slot freed when tile t was staged
        if (t + 2 < NTILES) {
            const float* src = srcBase + (size_t)(t + 2) * TN * DDIM;
#pragma unroll
            for (int i = 0; i < 8; i++) pf[t & 1][i] = *(const float4v*)(src + i * 32);
        }

        const char* buf = lds + (t & 1) * LDS_TILE;

        float4v acc[2][4];
#pragma unroll
        for (int mf = 0; mf < 2; mf++)
#pragma unroll
            for (int nf = 0; nf < 4; nf++) acc[mf][nf] = float4v{0.f, 0.f, 0.f, 0.f};

        // K loop: 8 k-blocks of 32
#pragma unroll
        for (int kb = 0; kb < 8; kb++) {
            half8 Bf[4];
#pragma unroll
            for (int nf = 0; nf < 4; nf++) {
                const int c = nf * 16 + m;                       // column in tile
                const int chunk = (kb * 4 + kq) ^ (m & 7);      // (c&7)==(m&7)
                Bf[nf] = *(const half8*)(buf + c * ROWB + (chunk << 4));
            }
#pragma unroll
            for (int mf = 0; mf < 2; mf++)
#pragma unroll
                for (int nf = 0; nf < 4; nf++)
                    acc[mf][nf] = __builtin_amdgcn_mfma_f32_16x16x32_f16(
                        Af[mf][kb], Bf[nf], acc[mf][nf], 0, 0, 0);
        }

        // epilogue: exp(logit - 20) folded into per-row sums
        // C/D layout: col = lane&15, row = kq*4 + reg
#pragma unroll
        for (int mf = 0; mf < 2; mf++)
#pragma unroll
            for (int nf = 0; nf < 4; nf++)
#pragma unroll
                for (int r = 0; r < 4; r++)
                    rowsum[mf][r] += __expf(fmaf(acc[mf][nf][r], 20.f, -20.f));

        // stage tile t+1 (waits pf[(t+1)&1] only -> vmcnt(8): t+2 stays in flight)
        if (t + 1 < NTILES) {
            char* wb = lds + ((t + 1) & 1) * LDS_TILE;
#pragma unroll
            for (int i = 0; i < 8; i++) {
                const int chunk = (sub >> 1) + i * 4;
                half4v h;
                h[0] = (_Float16)pf[(t + 1) & 1][i][0]; h[1] = (_Float16)pf[(t + 1) & 1][i][1];
                h[2] = (_Float16)pf[(t + 1) & 1][i][2]; h[3] = (_Float16)pf[(t + 1) & 1][i][3];
                *(half4v*)(wb + (sc * ROWB + (((chunk ^ (sc & 7)) << 4) | ((sub & 1) << 3)))) = h;
            }
            __syncthreads();
        }
    }

    // reduce rowsum across the 16 lanes sharing each row (lane&15 varies)
#pragma unroll
    for (int mf = 0; mf < 2; mf++)
#pragma unroll
        for (int r = 0; r < 4; r++) {
            float s = rowsum[mf][r];
            s += __shfl_xor(s, 1);
            s += __shfl_xor(s, 2);
            s += __shfl_xor(s, 4);
            s += __shfl_xor(s, 8);
            if (m == 0) {
                const int row = rBase + mf * 16 + kq * 4 + r;
                partial[row * NBLOCKS + blockIdx.x] = s;   // transposed
            }
        }
}

__global__ __launch_bounds__(256)
void finalize_kernel(const float* __restrict__ partial,  // [256][NBLOCKS]
                     const float* __restrict__ A,
                     const float* __restrict__ F,
                     const int* __restrict__ targets,
                     float* __restrict__ out)
{
    const int b = threadIdx.x;  // 256 threads, one per row

    // sum softmax denominators (exp offset = 20): contiguous per-thread row
    const float4v* p4 = (const float4v*)(partial + b * NBLOCKS);
    float sm0 = 0.f, sm1 = 0.f, sh0 = 0.f, sh1 = 0.f;
#pragma unroll 8
    for (int i = 0; i < 32; i += 2) {
        const float4v x = p4[i], y = p4[i + 1];
        sm0 += x[0] + x[1] + x[2] + x[3];
        sm1 += y[0] + y[1] + y[2] + y[3];
    }
#pragma unroll 8
    for (int i = 32; i < 64; i += 2) {
        const float4v x = p4[i], y = p4[i + 1];
        sh0 += x[0] + x[1] + x[2] + x[3];
        sh1 += y[0] + y[1] + y[2] + y[3];
    }
    const float sm = sm0 + sm1, sh = sh0 + sh1;

    // target logits in fp32
    const int t = targets[b];
    const float4v* a4 = (const float4v*)(A + b * DDIM);
    const float4v* fm = (const float4v*)(F + (size_t)t * DDIM);
    const float4v* fh = (const float4v*)(F + (size_t)(t + NHALF) * DDIM);
    float dm = 0.f, dh = 0.f;
#pragma unroll 8
    for (int i = 0; i < 64; i++) {
        const float4v a = a4[i], x = fm[i], y = fh[i];
        dm += a[0] * x[0] + a[1] * x[1] + a[2] * x[2] + a[3] * x[3];
        dh += a[0] * y[0] + a[1] * y[1] + a[2] * y[2] + a[3] * y[3];
    }

    // per-row CE terms: LSE - target_logit ; LSE = 20 + ln(sum)
    float cem = 20.f + __logf(sm) - dm * 20.f;
    float ceh = 20.f + __logf(sh) - dh * 20.f;

#pragma unroll
    for (int msk = 1; msk < 64; msk <<= 1) {
        cem += __shfl_xor(cem, msk);
        ceh += __shfl_xor(ceh, msk);
    }
    __shared__ float sb[8];
    const int wv = threadIdx.x >> 6;
    if ((threadIdx.x & 63) == 0) { sb[wv] = cem; sb[4 + wv] = ceh; }
    __syncthreads();
    if (threadIdx.x == 0) {
        const float cm = (sb[0] + sb[1] + sb[2] + sb[3]) * (1.f / 256.f);
        const float ch = (sb[4] + sb[5] + sb[6] + sb[7]) * (1.f / 256.f);
        const float rl = cm - 0.2f;
        out[0] = 0.5f * (ch + (rl > 0.f ? rl : 0.f));
    }
}

extern "C" void kernel_launch(void* const* d_in, const int* in_sizes, int n_in,
                              void* d_out, int out_size, void* d_ws, size_t ws_size,
                              hipStream_t stream) {
    const float* inputs   = (const float*)d_in[0];   // [256,256] f32
    const int*   targets  = (const int*)d_in[1];     // [256] int
    const float* features = (const float*)d_in[2];   // [131072,256] f32
    float* out = (float*)d_out;
    float* partial = (float*)d_ws;                   // 256*NBLOCKS floats = 256 KB

    gemm_lse_kernel<<<NBLOCKS, THREADS, 0, stream>>>(inputs, features, partial);
    finalize_kernel<<<1, 256, 0, stream>>>(partial, inputs, features, targets, out);
}

// Round 3
// 235.122 us; speedup vs baseline: 1.0303x; 1.0206x over previous
//
#include <hip/hip_runtime.h>

// ---------------------------------------------------------------------------
// loss = 0.5*(ce(hard) + relu(ce(mean)-R)),  logits = (inputs @ features^T)/TEMP
// B=256 rows, D=256, features rows = 131072 (first 65536 = "mean" half).
// Memory-bound: features (134 MB fp32) streams from HBM/L3 exactly once.
// f16 MFMA (16x16x32); exp-accumulate with fixed offset 20 (logits <= 20
// since rows are unit-norm); per-block partial denominators compose by +.
// R3: 1024-thread blocks, 16 waves x (16 rows x 64 cols) -> ~110 VGPRs ->
// 4 waves/SIMD (was 2). Distance-2 register prefetch kept. One barrier/tile.
// ---------------------------------------------------------------------------

typedef _Float16 half8 __attribute__((ext_vector_type(8)));
typedef _Float16 half4v __attribute__((ext_vector_type(4)));
typedef float float4v __attribute__((ext_vector_type(4)));

#define BROWS 256       // batch rows (M)
#define DDIM 256        // reduction (K)
#define NCOLS 131072    // total feature rows (2N)
#define NHALF 65536
#define CPB 512         // columns per block
#define TN 64           // columns per tile
#define NTILES (CPB / TN)          // 8
#define NBLOCKS (NCOLS / CPB)      // 256
#define THREADS 1024
#define ROWB 512                   // bytes per LDS tile row (256 halves)
#define LDS_TILE (TN * ROWB)       // 32768 B

__global__ __launch_bounds__(THREADS)
void gemm_lse_kernel(const float* __restrict__ A,   // [256][256]
                     const float* __restrict__ F,   // [131072][256]
                     float* __restrict__ partial)   // [256][NBLOCKS] (transposed)
{
    __shared__ __align__(16) char lds[2 * LDS_TILE];

    const int tid  = threadIdx.x;
    const int lane = tid & 63;
    const int w    = tid >> 6;       // wave 0..15 -> row band w*16
    const int m    = lane & 15;      // MFMA row/col within 16
    const int kq   = lane >> 4;      // k-quad 0..3
    const int colBase = blockIdx.x * CPB;
    const int rowBase = w * 16;

    // staging: 16 threads per column, 4 float4 each (64 B/thread)
    const int sc  = tid >> 4;        // staging col 0..63
    const int sub = tid & 15;        // 16 threads per column
    const float* srcBase = F + (size_t)(colBase + sc) * DDIM + sub * 4;

    // ---- issue loads for tiles 0 and 1 immediately (distance-2 queue) ----
    float4v pf[2][4];
#pragma unroll
    for (int i = 0; i < 4; i++) pf[0][i] = *(const float4v*)(srcBase + i * 64);
#pragma unroll
    for (int i = 0; i < 4; i++) pf[1][i] = *(const float4v*)(srcBase + TN * DDIM + i * 64);

    // ---- A fragments: 16-row band, all K, f16, in registers (32 VGPRs) ----
    // A-operand layout (16x16x32): A[m = lane&15][k = kq*8 + j]
    half8 Af[8];
    {
        const int r = rowBase + m;
        const float* ap = A + r * DDIM + kq * 8;
#pragma unroll
        for (int kb = 0; kb < 8; kb++) {
            const float4v x0 = *(const float4v*)(ap + kb * 32);
            const float4v x1 = *(const float4v*)(ap + kb * 32 + 4);
            half8 h;
            h[0] = (_Float16)x0[0]; h[1] = (_Float16)x0[1];
            h[2] = (_Float16)x0[2]; h[3] = (_Float16)x0[3];
            h[4] = (_Float16)x1[0]; h[5] = (_Float16)x1[1];
            h[6] = (_Float16)x1[2]; h[7] = (_Float16)x1[3];
            Af[kb] = h;
        }
    }

    // ---- stage tile 0 into LDS buffer 0 (waits only pf[0]; pf[1] in flight)
    // thread's float4 i covers k = sub*4 + i*64 -> f16 byte pos sub*8 + i*128
    // -> 16B chunk (sub>>1)+i*8, half-chunk (sub&1)*8; chunk XOR-swizzled by col.
#pragma unroll
    for (int i = 0; i < 4; i++) {
        const int chunk = (sub >> 1) + i * 8;
        half4v h;
        h[0] = (_Float16)pf[0][i][0]; h[1] = (_Float16)pf[0][i][1];
        h[2] = (_Float16)pf[0][i][2]; h[3] = (_Float16)pf[0][i][3];
        *(half4v*)(lds + (sc * ROWB + (((chunk ^ (sc & 7)) << 4) | ((sub & 1) << 3)))) = h;
    }
    __syncthreads();

    float rowsum[4];
#pragma unroll
    for (int r = 0; r < 4; r++) rowsum[r] = 0.f;

#pragma unroll 2
    for (int t = 0; t < NTILES; t++) {
        // issue loads for tile t+2 into the slot freed when tile t was staged
        if (t + 2 < NTILES) {
            const float* src = srcBase + (size_t)(t + 2) * TN * DDIM;
#pragma unroll
            for (int i = 0; i < 4; i++) pf[t & 1][i] = *(const float4v*)(src + i * 64);
        }

        const char* buf = lds + (t & 1) * LDS_TILE;

        float4v acc[4];
#pragma unroll
        for (int nf = 0; nf < 4; nf++) acc[nf] = float4v{0.f, 0.f, 0.f, 0.f};

        // K loop: 8 k-blocks of 32
#pragma unroll
        for (int kb = 0; kb < 8; kb++) {
            half8 Bf[4];
#pragma unroll
            for (int nf = 0; nf < 4; nf++) {
                const int c = nf * 16 + m;                  // column in tile
                const int chunk = (kb * 4 + kq) ^ (m & 7);  // (c&7)==(m&7)
                Bf[nf] = *(const half8*)(buf + c * ROWB + (chunk << 4));
            }
#pragma unroll
            for (int nf = 0; nf < 4; nf++)
                acc[nf] = __builtin_amdgcn_mfma_f32_16x16x32_f16(
                    Af[kb], Bf[nf], acc[nf], 0, 0, 0);
        }

        // epilogue: exp(logit - 20) folded into per-row sums
        // C/D layout: col = lane&15, row = kq*4 + reg
#pragma unroll
        for (int nf = 0; nf < 4; nf++)
#pragma unroll
            for (int r = 0; r < 4; r++)
                rowsum[r] += __expf(fmaf(acc[nf][r], 20.f, -20.f));

        // stage tile t+1 (its loads were issued 2 iterations ago)
        if (t + 1 < NTILES) {
            char* wb = lds + ((t + 1) & 1) * LDS_TILE;
#pragma unroll
            for (int i = 0; i < 4; i++) {
                const int chunk = (sub >> 1) + i * 8;
                half4v h;
                h[0] = (_Float16)pf[(t + 1) & 1][i][0]; h[1] = (_Float16)pf[(t + 1) & 1][i][1];
                h[2] = (_Float16)pf[(t + 1) & 1][i][2]; h[3] = (_Float16)pf[(t + 1) & 1][i][3];
                *(half4v*)(wb + (sc * ROWB + (((chunk ^ (sc & 7)) << 4) | ((sub & 1) << 3)))) = h;
            }
            __syncthreads();
        }
    }

    // reduce rowsum across the 16 lanes sharing each row (lane&15 varies)
#pragma unroll
    for (int r = 0; r < 4; r++) {
        float s = rowsum[r];
        s += __shfl_xor(s, 1);
        s += __shfl_xor(s, 2);
        s += __shfl_xor(s, 4);
        s += __shfl_xor(s, 8);
        if (m == 0) {
            const int row = rowBase + kq * 4 + r;
            partial[row * NBLOCKS + blockIdx.x] = s;   // transposed
        }
    }
}

__global__ __launch_bounds__(256)
void finalize_kernel(const float* __restrict__ partial,  // [256][NBLOCKS]
                     const float* __restrict__ A,
                     const float* __restrict__ F,
                     const int* __restrict__ targets,
                     float* __restrict__ out)
{
    const int b = threadIdx.x;  // 256 threads, one per row

    // sum softmax denominators (exp offset = 20): contiguous per-thread row
    const float4v* p4 = (const float4v*)(partial + b * NBLOCKS);
    float sm0 = 0.f, sm1 = 0.f, sh0 = 0.f, sh1 = 0.f;
#pragma unroll 8
    for (int i = 0; i < 32; i += 2) {
        const float4v x = p4[i], y = p4[i + 1];
        sm0 += x[0] + x[1] + x[2] + x[3];
        sm1 += y[0] + y[1] + y[2] + y[3];
    }
#pragma unroll 8
    for (int i = 32; i < 64; i += 2) {
        const float4v x = p4[i], y = p4[i + 1];
        sh0 += x[0] + x[1] + x[2] + x[3];
        sh1 += y[0] + y[1] + y[2] + y[3];
    }
    const float sm = sm0 + sm1, sh = sh0 + sh1;

    // target logits in fp32
    const int t = targets[b];
    const float4v* a4 = (const float4v*)(A + b * DDIM);
    const float4v* fm = (const float4v*)(F + (size_t)t * DDIM);
    const float4v* fh = (const float4v*)(F + (size_t)(t + NHALF) * DDIM);
    float dm = 0.f, dh = 0.f;
#pragma unroll 8
    for (int i = 0; i < 64; i++) {
        const float4v a = a4[i], x = fm[i], y = fh[i];
        dm += a[0] * x[0] + a[1] * x[1] + a[2] * x[2] + a[3] * x[3];
        dh += a[0] * y[0] + a[1] * y[1] + a[2] * y[2] + a[3] * y[3];
    }

    // per-row CE terms: LSE - target_logit ; LSE = 20 + ln(sum)
    float cem = 20.f + __logf(sm) - dm * 20.f;
    float ceh = 20.f + __logf(sh) - dh * 20.f;

#pragma unroll
    for (int msk = 1; msk < 64; msk <<= 1) {
        cem += __shfl_xor(cem, msk);
        ceh += __shfl_xor(ceh, msk);
    }
    __shared__ float sb[8];
    const int wv = threadIdx.x >> 6;
    if ((threadIdx.x & 63) == 0) { sb[wv] = cem; sb[4 + wv] = ceh; }
    __syncthreads();
    if (threadIdx.x == 0) {
        const float cm = (sb[0] + sb[1] + sb[2] + sb[3]) * (1.f / 256.f);
        const float ch = (sb[4] + sb[5] + sb[6] + sb[7]) * (1.f / 256.f);
        const float rl = cm - 0.2f;
        out[0] = 0.5f * (ch + (rl > 0.f ? rl : 0.f));
    }
}

extern "C" void kernel_launch(void* const* d_in, const int* in_sizes, int n_in,
                              void* d_out, int out_size, void* d_ws, size_t ws_size,
                              hipStream_t stream) {
    const float* inputs   = (const float*)d_in[0];   // [256,256] f32
    const int*   targets  = (const int*)d_in[1];     // [256] int
    const float* features = (const float*)d_in[2];   // [131072,256] f32
    float* out = (float*)d_out;
    float* partial = (float*)d_ws;                   // 256*NBLOCKS floats = 256 KB

    gemm_lse_kernel<<<NBLOCKS, THREADS, 0, stream>>>(inputs, features, partial);
    finalize_kernel<<<1, 256, 0, stream>>>(partial, inputs, features, targets, out);
}

// Round 4
// 207.142 us; speedup vs baseline: 1.1694x; 1.1351x over previous
//
#include <hip/hip_runtime.h>

// ---------------------------------------------------------------------------
// loss = 0.5*(ce(hard) + relu(ce(mean)-R)),  logits = (inputs @ features^T)/TEMP
// B=256 rows, D=256, features rows = 131072 (first 65536 = "mean" half).
// Memory-bound: features (134 MB fp32) streams from HBM/L3 exactly once;
// floor = 134 MB / ~6.9 TB/s ~= 19.4 us. f16 MFMA (16x16x32); exp-accumulate
// with fixed offset 20 (logits <= 20, unit-norm rows); partials compose by +.
// R3: 1024-thread blocks, 16 waves, ~110 VGPR -> 4 waves/SIMD.
// R4: finalize split: per-row stage parallel over 256 blocks (was 1 block,
// latency-bound), then a tiny scalar-reduce kernel.
// ---------------------------------------------------------------------------

typedef _Float16 half8 __attribute__((ext_vector_type(8)));
typedef _Float16 half4v __attribute__((ext_vector_type(4)));
typedef float float4v __attribute__((ext_vector_type(4)));
typedef float float2v __attribute__((ext_vector_type(2)));

#define BROWS 256       // batch rows (M)
#define DDIM 256        // reduction (K)
#define NCOLS 131072    // total feature rows (2N)
#define NHALF 65536
#define CPB 512         // columns per block
#define TN 64           // columns per tile
#define NTILES (CPB / TN)          // 8
#define NBLOCKS (NCOLS / CPB)      // 256
#define THREADS 1024
#define ROWB 512                   // bytes per LDS tile row (256 halves)
#define LDS_TILE (TN * ROWB)       // 32768 B

__global__ __launch_bounds__(THREADS)
void gemm_lse_kernel(const float* __restrict__ A,   // [256][256]
                     const float* __restrict__ F,   // [131072][256]
                     float* __restrict__ partial)   // [256][NBLOCKS] (transposed)
{
    __shared__ __align__(16) char lds[2 * LDS_TILE];

    const int tid  = threadIdx.x;
    const int lane = tid & 63;
    const int w    = tid >> 6;       // wave 0..15 -> row band w*16
    const int m    = lane & 15;      // MFMA row/col within 16
    const int kq   = lane >> 4;      // k-quad 0..3
    const int colBase = blockIdx.x * CPB;
    const int rowBase = w * 16;

    // staging: 16 threads per column, 4 float4 each (64 B/thread)
    const int sc  = tid >> 4;        // staging col 0..63
    const int sub = tid & 15;        // 16 threads per column
    const float* srcBase = F + (size_t)(colBase + sc) * DDIM + sub * 4;

    // ---- issue loads for tiles 0 and 1 immediately (distance-2 queue) ----
    float4v pf[2][4];
#pragma unroll
    for (int i = 0; i < 4; i++) pf[0][i] = *(const float4v*)(srcBase + i * 64);
#pragma unroll
    for (int i = 0; i < 4; i++) pf[1][i] = *(const float4v*)(srcBase + TN * DDIM + i * 64);

    // ---- A fragments: 16-row band, all K, f16, in registers (32 VGPRs) ----
    // A-operand layout (16x16x32): A[m = lane&15][k = kq*8 + j]
    half8 Af[8];
    {
        const int r = rowBase + m;
        const float* ap = A + r * DDIM + kq * 8;
#pragma unroll
        for (int kb = 0; kb < 8; kb++) {
            const float4v x0 = *(const float4v*)(ap + kb * 32);
            const float4v x1 = *(const float4v*)(ap + kb * 32 + 4);
            half8 h;
            h[0] = (_Float16)x0[0]; h[1] = (_Float16)x0[1];
            h[2] = (_Float16)x0[2]; h[3] = (_Float16)x0[3];
            h[4] = (_Float16)x1[0]; h[5] = (_Float16)x1[1];
            h[6] = (_Float16)x1[2]; h[7] = (_Float16)x1[3];
            Af[kb] = h;
        }
    }

    // ---- stage tile 0 into LDS buffer 0 (waits only pf[0]; pf[1] in flight)
    // thread's float4 i covers k = sub*4 + i*64 -> f16 byte pos sub*8 + i*128
    // -> 16B chunk (sub>>1)+i*8, half-chunk (sub&1)*8; chunk XOR-swizzled by col.
#pragma unroll
    for (int i = 0; i < 4; i++) {
        const int chunk = (sub >> 1) + i * 8;
        half4v h;
        h[0] = (_Float16)pf[0][i][0]; h[1] = (_Float16)pf[0][i][1];
        h[2] = (_Float16)pf[0][i][2]; h[3] = (_Float16)pf[0][i][3];
        *(half4v*)(lds + (sc * ROWB + (((chunk ^ (sc & 7)) << 4) | ((sub & 1) << 3)))) = h;
    }
    __syncthreads();

    float rowsum[4];
#pragma unroll
    for (int r = 0; r < 4; r++) rowsum[r] = 0.f;

#pragma unroll 2
    for (int t = 0; t < NTILES; t++) {
        // issue loads for tile t+2 into the slot freed when tile t was staged
        if (t + 2 < NTILES) {
            const float* src = srcBase + (size_t)(t + 2) * TN * DDIM;
#pragma unroll
            for (int i = 0; i < 4; i++) pf[t & 1][i] = *(const float4v*)(src + i * 64);
        }

        const char* buf = lds + (t & 1) * LDS_TILE;

        float4v acc[4];
#pragma unroll
        for (int nf = 0; nf < 4; nf++) acc[nf] = float4v{0.f, 0.f, 0.f, 0.f};

        // K loop: 8 k-blocks of 32
#pragma unroll
        for (int kb = 0; kb < 8; kb++) {
            half8 Bf[4];
#pragma unroll
            for (int nf = 0; nf < 4; nf++) {
                const int c = nf * 16 + m;                  // column in tile
                const int chunk = (kb * 4 + kq) ^ (m & 7);  // (c&7)==(m&7)
                Bf[nf] = *(const half8*)(buf + c * ROWB + (chunk << 4));
            }
#pragma unroll
            for (int nf = 0; nf < 4; nf++)
                acc[nf] = __builtin_amdgcn_mfma_f32_16x16x32_f16(
                    Af[kb], Bf[nf], acc[nf], 0, 0, 0);
        }

        // epilogue: exp(logit - 20) folded into per-row sums
        // C/D layout: col = lane&15, row = kq*4 + reg
#pragma unroll
        for (int nf = 0; nf < 4; nf++)
#pragma unroll
            for (int r = 0; r < 4; r++)
                rowsum[r] += __expf(fmaf(acc[nf][r], 20.f, -20.f));

        // stage tile t+1 (its loads were issued 2 iterations ago)
        if (t + 1 < NTILES) {
            char* wb = lds + ((t + 1) & 1) * LDS_TILE;
#pragma unroll
            for (int i = 0; i < 4; i++) {
                const int chunk = (sub >> 1) + i * 8;
                half4v h;
                h[0] = (_Float16)pf[(t + 1) & 1][i][0]; h[1] = (_Float16)pf[(t + 1) & 1][i][1];
                h[2] = (_Float16)pf[(t + 1) & 1][i][2]; h[3] = (_Float16)pf[(t + 1) & 1][i][3];
                *(half4v*)(wb + (sc * ROWB + (((chunk ^ (sc & 7)) << 4) | ((sub & 1) << 3)))) = h;
            }
            __syncthreads();
        }
    }

    // reduce rowsum across the 16 lanes sharing each row (lane&15 varies)
#pragma unroll
    for (int r = 0; r < 4; r++) {
        float s = rowsum[r];
        s += __shfl_xor(s, 1);
        s += __shfl_xor(s, 2);
        s += __shfl_xor(s, 4);
        s += __shfl_xor(s, 8);
        if (m == 0) {
            const int row = rowBase + kq * 4 + r;
            partial[row * NBLOCKS + blockIdx.x] = s;   // transposed
        }
    }
}

// One block per batch row, 64 threads: per-row CE terms -> ce[b] = {cem, ceh}.
__global__ __launch_bounds__(64)
void finalize_rows(const float* __restrict__ partial,  // [256][NBLOCKS]
                   const float* __restrict__ A,
                   const float* __restrict__ F,
                   const int* __restrict__ targets,
                   float2v* __restrict__ ce)           // [256]
{
    const int b = blockIdx.x;
    const int l = threadIdx.x;   // 0..63

    // partials row: 256 floats; lane l sums one float4.
    // p4[0..31] = mean half (blocks 0..127), p4[32..63] = hard half.
    const float4v* p4 = (const float4v*)(partial + b * NBLOCKS);
    const float4v x = p4[l];
    const float s = x[0] + x[1] + x[2] + x[3];
    float smv = (l < 32) ? s : 0.f;
    float shv = (l < 32) ? 0.f : s;

    // target-logit dots: lane l covers D-elements [4l, 4l+4)
    const int t = targets[b];
    const float4v a  = *(const float4v*)(A + b * DDIM + l * 4);
    const float4v xm = *(const float4v*)(F + (size_t)t * DDIM + l * 4);
    const float4v xh = *(const float4v*)(F + (size_t)(t + NHALF) * DDIM + l * 4);
    float dm = a[0] * xm[0] + a[1] * xm[1] + a[2] * xm[2] + a[3] * xm[3];
    float dh = a[0] * xh[0] + a[1] * xh[1] + a[2] * xh[2] + a[3] * xh[3];

#pragma unroll
    for (int msk = 1; msk < 64; msk <<= 1) {
        smv += __shfl_xor(smv, msk);
        shv += __shfl_xor(shv, msk);
        dm  += __shfl_xor(dm, msk);
        dh  += __shfl_xor(dh, msk);
    }
    if (l == 0) {
        // CE = LSE - target_logit ; LSE = 20 + ln(sum of exp(logit-20))
        float2v r;
        r[0] = 20.f + __logf(smv) - dm * 20.f;
        r[1] = 20.f + __logf(shv) - dh * 20.f;
        ce[b] = r;
    }
}

__global__ __launch_bounds__(256)
void finalize_loss(const float2v* __restrict__ ce,  // [256]
                   float* __restrict__ out)
{
    const float2v c = ce[threadIdx.x];
    float cem = c[0], ceh = c[1];
#pragma unroll
    for (int msk = 1; msk < 64; msk <<= 1) {
        cem += __shfl_xor(cem, msk);
        ceh += __shfl_xor(ceh, msk);
    }
    __shared__ float sb[8];
    const int wv = threadIdx.x >> 6;
    if ((threadIdx.x & 63) == 0) { sb[wv] = cem; sb[4 + wv] = ceh; }
    __syncthreads();
    if (threadIdx.x == 0) {
        const float cm = (sb[0] + sb[1] + sb[2] + sb[3]) * (1.f / 256.f);
        const float ch = (sb[4] + sb[5] + sb[6] + sb[7]) * (1.f / 256.f);
        const float rl = cm - 0.2f;
        out[0] = 0.5f * (ch + (rl > 0.f ? rl : 0.f));
    }
}

extern "C" void kernel_launch(void* const* d_in, const int* in_sizes, int n_in,
                              void* d_out, int out_size, void* d_ws, size_t ws_size,
                              hipStream_t stream) {
    const float* inputs   = (const float*)d_in[0];   // [256,256] f32
    const int*   targets  = (const int*)d_in[1];     // [256] int
    const float* features = (const float*)d_in[2];   // [131072,256] f32
    float* out = (float*)d_out;
    float* partial = (float*)d_ws;                   // 256*NBLOCKS floats = 256 KB
    float2v* ce = (float2v*)((char*)d_ws + BROWS * NBLOCKS * sizeof(float)); // 2 KB

    gemm_lse_kernel<<<NBLOCKS, THREADS, 0, stream>>>(inputs, features, partial);
    finalize_rows<<<BROWS, 64, 0, stream>>>(partial, inputs, features, targets, ce);
    finalize_loss<<<1, 256, 0, stream>>>(ce, out);
}